// Round 3
// baseline (304.222 us; speedup 1.0000x reference)
//
#include <hip/hip_runtime.h>
#include <stdint.h>
#include <string.h>

typedef unsigned short u16;
typedef __bf16 bf16x8_t __attribute__((ext_vector_type(8)));
typedef float f32x4 __attribute__((ext_vector_type(4)));

#define T_LEN 2048
#define NHEADS 16
#define DHEAD 64
#define DMODEL 1024
#define QSCALE 0.1803368801111f  /* 0.125 * log2(e): softmax done in exp2 domain */
#define NSLOT 80                 /* chunk-slots per (b,h): sum over qt of ceil((qt+1)/8) */

__device__ __forceinline__ u16 f2bf(float f) {
  union { float f; uint32_t u; } v; v.f = f;
  uint32_t r = v.u + 0x7FFFu + ((v.u >> 16) & 1u);
  return (u16)(r >> 16);
}
__device__ __forceinline__ float bf2f(u16 u) {
  union { uint32_t u; float f; } v; v.u = (uint32_t)u << 16; return v.f;
}

// async global->LDS, 16B per lane, dest = wave-uniform base + lane*16
__device__ __forceinline__ void gload16(const u16* g, u16* l) {
  __builtin_amdgcn_global_load_lds((const __attribute__((address_space(1))) void*)g,
                                   (__attribute__((address_space(3))) void*)l, 16, 0, 0);
}

// ---------------- fp32 -> bf16 conversion ----------------
__global__ void cvt_bf16_k(const float* __restrict__ s, u16* __restrict__ d, int n) {
  int i = (blockIdx.x * blockDim.x + threadIdx.x) * 4;
  if (i >= n) return;
  float4 f = *(const float4*)(s + i);
  u16 o[4] = { f2bf(f.x), f2bf(f.y), f2bf(f.z), f2bf(f.w) };
  *(uint2*)(d + i) = *(const uint2*)o;
}

// fused conversion of the 4 weight matrices (one launch instead of four)
__global__ void cvt_w_k(const float* __restrict__ wq, const float* __restrict__ wk,
                        const float* __restrict__ wv, const float* __restrict__ wp,
                        u16* __restrict__ dqkv, u16* __restrict__ dp) {
  int which = blockIdx.y;
  const float* s = which == 0 ? wq : (which == 1 ? wk : (which == 2 ? wv : wp));
  u16* d = which == 3 ? dp : dqkv + (size_t)which * 1048576;
  int i = (blockIdx.x * blockDim.x + threadIdx.x) * 4;
  float4 f = *(const float4*)(s + i);
  u16 o[4] = { f2bf(f.x), f2bf(f.y), f2bf(f.z), f2bf(f.w) };
  *(uint2*)(d + i) = *(const uint2*)o;
}

// ---------------- GEMM: C = A(bf16[M,K]) * Bw(bf16[N,K])^T + bias ----------------
// MODE 0: fp32 out [M,N] = o0, bias b0
// MODE 3: fused QKV epilogue; n-section 0 -> Q scatter [B,H,T,Dh] *QSCALE (o0,b0)
//                             section 1 -> K scatter [B,H,T,Dh]          (o1,b1)
//                             section 2 -> V scatter [B,H,Dh,T]          (o2,b2)
template <int TM, int TN, int MODE>
__global__ __launch_bounds__(256, 2) void gemm_k(
    const u16* __restrict__ A, const u16* __restrict__ Bw,
    const float* __restrict__ b0, const float* __restrict__ b1, const float* __restrict__ b2,
    void* __restrict__ o0, void* __restrict__ o1, void* __restrict__ o2,
    int M, int N, int K)
{
  __shared__ __align__(16) u16 As[TM][32];  // unpadded: global_load_lds lane-contiguous
  __shared__ __align__(16) u16 Bs[TN][32];
  const int m0 = blockIdx.x * TM, n0 = blockIdx.y * TN;
  const int tid = threadIdx.x, lane = tid & 63, w = tid >> 6;
  const int col = lane & 15, quad = lane >> 4;
  constexpr int WM = TM / 2, WN = TN / 2;
  const int wm = (w >> 1) * WM, wn = (w & 1) * WN;
  constexpr int NI = WM / 16, NJ = WN / 16;
  const int lrow = lane >> 2, lk = (lane & 3) * 8;

  f32x4 acc[NI][NJ] = {};

  for (int k0 = 0; k0 < K; k0 += 32) {
    __syncthreads();
#pragma unroll
    for (int i = 0; i < TM / 64; i++) {
      int r = (i * 4 + w) * 16;
      gload16(&A[(size_t)(m0 + r + lrow) * K + k0 + lk], &As[r][0]);
    }
#pragma unroll
    for (int i = 0; i < TN / 64; i++) {
      int r = (i * 4 + w) * 16;
      gload16(&Bw[(size_t)(n0 + r + lrow) * K + k0 + lk], &Bs[r][0]);
    }
    __syncthreads();
    bf16x8_t af[NI], bfr[NJ];
#pragma unroll
    for (int i = 0; i < NI; i++) af[i]  = *(const bf16x8_t*)&As[wm + i * 16 + col][quad * 8];
#pragma unroll
    for (int j = 0; j < NJ; j++) bfr[j] = *(const bf16x8_t*)&Bs[wn + j * 16 + col][quad * 8];
#pragma unroll
    for (int i = 0; i < NI; i++)
#pragma unroll
      for (int j = 0; j < NJ; j++)
        acc[i][j] = __builtin_amdgcn_mfma_f32_16x16x32_bf16(af[i], bfr[j], acc[i][j], 0, 0, 0);
  }

#pragma unroll
  for (int i = 0; i < NI; i++) {
#pragma unroll
    for (int j = 0; j < NJ; j++) {
      int ncol = n0 + wn + j * 16 + col;
      if (MODE == 0) {
        float bias = b0[ncol];
#pragma unroll
        for (int r = 0; r < 4; r++) {
          int m = m0 + wm + i * 16 + quad * 4 + r;  // C/D: row=quad*4+r, col=lane&15
          ((float*)o0)[(size_t)m * N + ncol] = acc[i][j][r] + bias;
        }
      } else {
        int sect = ncol >> 10, nc = ncol & 1023;
        const float* bp = sect == 0 ? b0 : (sect == 1 ? b1 : b2);
        u16* op = sect == 0 ? (u16*)o0 : (sect == 1 ? (u16*)o1 : (u16*)o2);
        float bias = bp[nc];
        float scal = sect == 0 ? QSCALE : 1.0f;
        int h = nc >> 6, d = nc & 63;
#pragma unroll
        for (int r = 0; r < 4; r++) {
          int m = m0 + wm + i * 16 + quad * 4 + r;
          int b = m >> 11, t = m & 2047;
          float v = (acc[i][j][r] + bias) * scal;
          size_t idx = sect < 2 ? ((((size_t)(b * NHEADS + h)) * T_LEN + t) * DHEAD + d)
                                : ((((size_t)(b * NHEADS + h)) * DHEAD + d) * T_LEN + t);
          op[idx] = f2bf(v);
        }
      }
    }
  }
}

// ---------------- Flash attention, split-K for occupancy ----------------
// Each block = one (bh, qt, key-chunk of <=8 key-tiles). 2560 blocks total -> ~8 blocks/CU
// resident (vs 2 before). Writes unnormalized partial O (bf16) + per-row m,l (fp32, log2 dom).
__global__ __launch_bounds__(256, 2) void attn_k(
    const u16* __restrict__ Q, const u16* __restrict__ Kb, const u16* __restrict__ Vt,
    u16* __restrict__ Opart, float* __restrict__ Mp, float* __restrict__ Lp)
{
  __shared__ __align__(16) u16 Ps[4][16][68];  // per-wave; stride 68 -> conflict-free
  const int slot = blockIdx.x;   // 0..79
  const int bh = blockIdx.y;     // 0..31
  const int tid = threadIdx.x, lane = tid & 63, w = tid >> 6;
  const int col = lane & 15, quad = lane >> 4;

  // slot -> (qt, chunk): qt 0-7:1 chunk, 8-15:2, 16-23:3, 24-31:4
  int qt, c;
  if (slot < 8)       { qt = slot;                c = 0; }
  else if (slot < 24) { qt = 8 + (slot - 8) / 2;  c = (slot - 8) % 2; }
  else if (slot < 48) { qt = 16 + (slot - 24) / 3; c = (slot - 24) % 3; }
  else                { qt = 24 + (slot - 48) / 4; c = (slot - 48) % 4; }
  const int ktBeg = c * 8;
  const int ktEnd = min(ktBeg + 8, qt + 1);
  const int qw = qt * 64 + w * 16;

  bf16x8_t qf0, qf1;
  {
    const u16* p = Q + ((size_t)bh * T_LEN + qw + col) * DHEAD + quad * 8;
    qf0 = *(const bf16x8_t*)p;
    qf1 = *(const bf16x8_t*)(p + 32);
  }

  float m_i[4], l_i[4];
#pragma unroll
  for (int r = 0; r < 4; r++) { m_i[r] = -1e30f; l_i[r] = 0.f; }
  f32x4 o[4] = {};

  for (int kt = ktBeg; kt < ktEnd; ++kt) {
    const int k0 = kt * 64;
    const u16* kp = Kb + ((size_t)bh * T_LEN + k0 + col) * DHEAD + quad * 8;
    bf16x8_t kfa[4], kfb[4];
#pragma unroll
    for (int nt = 0; nt < 4; nt++) {
      kfa[nt] = *(const bf16x8_t*)(kp + nt * 16 * DHEAD);
      kfb[nt] = *(const bf16x8_t*)(kp + nt * 16 * DHEAD + 32);
    }
    f32x4 s[4];
#pragma unroll
    for (int nt = 0; nt < 4; nt++) {
      f32x4 a = {};
      a = __builtin_amdgcn_mfma_f32_16x16x32_bf16(qf0, kfa[nt], a, 0, 0, 0);
      a = __builtin_amdgcn_mfma_f32_16x16x32_bf16(qf1, kfb[nt], a, 0, 0, 0);
      s[nt] = a;
    }
    bf16x8_t vf[4][2];
#pragma unroll
    for (int dt = 0; dt < 4; dt++)
#pragma unroll
      for (int ks = 0; ks < 2; ks++)
        vf[dt][ks] = *(const bf16x8_t*)&Vt[((size_t)bh * DHEAD + dt * 16 + col) * T_LEN +
                                           k0 + ks * 32 + quad * 8];

    const bool diag = (kt == qt);
#pragma unroll
    for (int r = 0; r < 4; r++) {
      const int qrow = qw + quad * 4 + r;
      float mx = -1e30f;
      if (diag) {
#pragma unroll
        for (int nt = 0; nt < 4; nt++) {
          float v = s[nt][r];
          if ((k0 + nt * 16 + col) > qrow) v = -1e30f;
          s[nt][r] = v;
          mx = fmaxf(mx, v);
        }
      } else {
#pragma unroll
        for (int nt = 0; nt < 4; nt++) mx = fmaxf(mx, s[nt][r]);
      }
#pragma unroll
      for (int off = 1; off < 16; off <<= 1)
        mx = fmaxf(mx, __shfl_xor(mx, off));
      float mnew = fmaxf(m_i[r], mx);
      float alpha = exp2f(m_i[r] - mnew);
      float sum = 0.f;
#pragma unroll
      for (int nt = 0; nt < 4; nt++) {
        float p = exp2f(s[nt][r] - mnew);
        s[nt][r] = p;
        sum += p;
      }
#pragma unroll
      for (int off = 1; off < 16; off <<= 1)
        sum += __shfl_xor(sum, off);
      l_i[r] = l_i[r] * alpha + sum;
      m_i[r] = mnew;
#pragma unroll
      for (int dt = 0; dt < 4; dt++) o[dt][r] *= alpha;
#pragma unroll
      for (int nt = 0; nt < 4; nt++)
        Ps[w][quad * 4 + r][nt * 16 + col] = f2bf(s[nt][r]);
    }
#pragma unroll
    for (int ks = 0; ks < 2; ks++) {
      bf16x8_t pf = *(const bf16x8_t*)&Ps[w][col][ks * 32 + quad * 8];
#pragma unroll
      for (int dt = 0; dt < 4; dt++)
        o[dt] = __builtin_amdgcn_mfma_f32_16x16x32_bf16(pf, vf[dt][ks], o[dt], 0, 0, 0);
    }
  }

  // epilogue: partial (unnormalized) O + m,l per row
  const int p = bh * NSLOT + slot;
#pragma unroll
  for (int r = 0; r < 4; r++) {
    int row = w * 16 + quad * 4 + r;
    if (col == 0) {
      Mp[p * 64 + row] = m_i[r];
      Lp[p * 64 + row] = l_i[r];
    }
#pragma unroll
    for (int dt = 0; dt < 4; dt++)
      Opart[(((size_t)p * 64) + row) * 64 + dt * 16 + col] = f2bf(o[dt][r]);
  }
}

// ---------------- combine partials -> y_att [B,T,C] bf16 ----------------
__global__ __launch_bounds__(256) void attn_combine_k(
    const u16* __restrict__ Opart, const float* __restrict__ Mp, const float* __restrict__ Lp,
    u16* __restrict__ Y)
{
  const int qt = blockIdx.x, bh = blockIdx.y;
  int nc, base;
  if (qt < 8)       { nc = 1; base = qt; }
  else if (qt < 16) { nc = 2; base = 8 + (qt - 8) * 2; }
  else if (qt < 24) { nc = 3; base = 24 + (qt - 16) * 3; }
  else              { nc = 4; base = 48 + (qt - 24) * 4; }
  const int tid = threadIdx.x;
  const int r = tid >> 2, cs = (tid & 3) * 16;
  const int b = bh >> 4, h = bh & 15;

  float mv[4], lv[4], m = -1e30f;
  for (int c = 0; c < nc; c++) {
    int p = bh * NSLOT + base + c;
    mv[c] = Mp[p * 64 + r];
    lv[c] = Lp[p * 64 + r];
    m = fmaxf(m, mv[c]);
  }
  float acc[16] = {};
  float L = 0.f;
  for (int c = 0; c < nc; c++) {
    int p = bh * NSLOT + base + c;
    float wgt = exp2f(mv[c] - m);
    L += lv[c] * wgt;
    const u16* op = Opart + (((size_t)p * 64) + r) * 64 + cs;
    u16 buf[16];
    *(uint4*)buf = *(const uint4*)op;
    *(uint4*)(buf + 8) = *(const uint4*)(op + 8);
#pragma unroll
    for (int j = 0; j < 16; j++) acc[j] += wgt * bf2f(buf[j]);
  }
  float inv = 1.0f / L;
  u16 outv[16];
#pragma unroll
  for (int j = 0; j < 16; j++) outv[j] = f2bf(acc[j] * inv);
  u16* yp = Y + ((size_t)(b * T_LEN + qt * 64 + r)) * DMODEL + h * DHEAD + cs;
  *(uint4*)yp = *(const uint4*)outv;
  *(uint4*)(yp + 8) = *(const uint4*)(outv + 8);
}

// ---------------- launch ----------------
extern "C" void kernel_launch(void* const* d_in, const int* in_sizes, int n_in,
                              void* d_out, int out_size, void* d_ws, size_t ws_size,
                              hipStream_t stream) {
  const float* x  = (const float*)d_in[0];
  const float* Wk = (const float*)d_in[1];
  const float* bk = (const float*)d_in[2];
  const float* Wq = (const float*)d_in[3];
  const float* bq = (const float*)d_in[4];
  const float* Wv = (const float*)d_in[5];
  const float* bv = (const float*)d_in[6];
  const float* Wp = (const float*)d_in[7];
  const float* bp = (const float*)d_in[8];

  char* ws = (char*)d_ws;
  const size_t MB = 1u << 20;
  u16* xb    = (u16*)(ws);            // 8 MB : x bf16 [4096,1024]
  u16* wqkv  = (u16*)(ws + 8 * MB);   // 6 MB : [Wq;Wk;Wv] bf16 [3072,1024]
  u16* wpb   = (u16*)(ws + 14 * MB);  // 2 MB
  u16* qb    = (u16*)(ws + 16 * MB);  // 8 MB : [B,H,T,64] (pre-scaled)
  u16* kb    = (u16*)(ws + 24 * MB);  // 8 MB : [B,H,T,64]
  u16* vtb   = (u16*)(ws + 32 * MB);  // 8 MB : [B,H,64,T]
  u16* yatt  = (u16*)(ws + 40 * MB);  // 8 MB : [B,T,1024]
  u16* opart = (u16*)(ws + 48 * MB);  // 20 MB: [2560][64][64] bf16
  float* Mp  = (float*)(ws + 68 * MB);          // 0.625 MB
  float* Lp  = (float*)(ws + 68 * MB + 655360); // 0.625 MB

  cvt_bf16_k<<<4096, 256, 0, stream>>>(x, xb, 4194304);
  dim3 gw(1024, 4);
  cvt_w_k<<<gw, 256, 0, stream>>>(Wq, Wk, Wv, Wp, wqkv, wpb);

  // fused QKV projection: [4096,1024] x [3072,1024]^T
  dim3 gqkv(32, 24);
  gemm_k<128, 128, 3><<<gqkv, 256, 0, stream>>>(xb, wqkv, bq, bk, bv,
                                                qb, kb, vtb, 4096, 3072, 1024);

  dim3 ga(NSLOT, 32);
  attn_k<<<ga, 256, 0, stream>>>(qb, kb, vtb, opart, Mp, Lp);
  dim3 gc(32, 32);
  attn_combine_k<<<gc, 256, 0, stream>>>(opart, Mp, Lp, yatt);

  // final projection -> fp32 out
  dim3 gp(32, 16);
  gemm_k<128, 64, 0><<<gp, 256, 0, stream>>>(yatt, wpb, bp, nullptr, nullptr,
                                             d_out, nullptr, nullptr, 4096, 1024, 1024);
}